// Round 19
// baseline (2627.917 us; speedup 1.0000x reference)
//
#include <hip/hip_runtime.h>
#include <math.h>

#define BB 64      // batch
#define SS 512     // seq len
#define EE 128     // embed dim
#define HH 256     // hidden
#define NC 9       // classes
#define G4 1024    // 4*H gates (one direction)
#define TCLOG 7
#define TC 128     // time chunk
#define NCH (SS / TC)

#define KLQ 9      // int8 k16 chunks cached in LDS = 144 KB; chunks 9..15 streamed int4

typedef _Float16 half2v __attribute__((ext_vector_type(2)));

// ---------- activations ----------
__device__ __forceinline__ float sigf(float x) {
    return 1.0f / (1.0f + __expf(-x));
}
__device__ __forceinline__ float tanhfast(float x) {
    float a = fabsf(x);
    float e = __expf(-2.0f * a);
    float t = (1.0f - e) / (1.0f + e);
    return copysignf(t, x);
}
__device__ __forceinline__ float dot8h(uint4 w, uint4 h, float acc) {
    acc = __builtin_amdgcn_fdot2(__builtin_bit_cast(half2v, w.x),
                                 __builtin_bit_cast(half2v, h.x), acc, false);
    acc = __builtin_amdgcn_fdot2(__builtin_bit_cast(half2v, w.y),
                                 __builtin_bit_cast(half2v, h.y), acc, false);
    acc = __builtin_amdgcn_fdot2(__builtin_bit_cast(half2v, w.z),
                                 __builtin_bit_cast(half2v, h.z), acc, false);
    acc = __builtin_amdgcn_fdot2(__builtin_bit_cast(half2v, w.w),
                                 __builtin_bit_cast(half2v, h.w), acc, false);
    return acc;
}
__device__ __forceinline__ int dot16q(uint4 w, uint4 h, int acc) {
    acc = __builtin_amdgcn_sdot4((int)w.x, (int)h.x, acc, false);
    acc = __builtin_amdgcn_sdot4((int)w.y, (int)h.y, acc, false);
    acc = __builtin_amdgcn_sdot4((int)w.z, (int)h.z, acc, false);
    acc = __builtin_amdgcn_sdot4((int)w.w, (int)h.w, acc, false);
    return acc;
}
__device__ __forceinline__ ushort f16b(float x) {
    return __builtin_bit_cast(ushort, (_Float16)x);
}

// ---------- w_hh quantize: int8 (chunks 0..8, j-order) + int4 bias-8 (chunks 9..15) ----------
__global__ void quant_whh(const float* __restrict__ whh, uint* __restrict__ wTq,
                          uint* __restrict__ wTq4,
                          float* __restrict__ swf, float* __restrict__ swf4) {
    const int row = blockIdx.x;        // 0..2047
    const int t = threadIdx.x;         // 0..63, owns k = 4t..4t+3
    float4 v = *(const float4*)(whh + (long)row * 256 + t * 4);
    float mloc = fmaxf(fmaxf(fabsf(v.x), fabsf(v.y)), fmaxf(fabsf(v.z), fabsf(v.w)));
    float mx = mloc;
    #pragma unroll
    for (int o = 32; o > 0; o >>= 1) mx = fmaxf(mx, __shfl_xor(mx, o));
    const int dir = row >> 10, j = row & 1023;
    // int8 (all chunks; scan uses 0..8)
    {
        float inv = (mx > 0.f) ? 127.f / mx : 0.f;
        int q0 = (int)rintf(v.x * inv) & 255;
        int q1 = (int)rintf(v.y * inv) & 255;
        int q2 = (int)rintf(v.z * inv) & 255;
        int q3 = (int)rintf(v.w * inv) & 255;
        uint u = (uint)q0 | ((uint)q1 << 8) | ((uint)q2 << 16) | ((uint)q3 << 24);
        const int kc = t >> 2, l4 = t & 3;
        wTq[(((long)(dir * 16 + kc) * 1024 + j) << 2) + l4] = u;
    }
    // int4 bias-8 for streamed k in [144,256)  (lanes t >= 36)
    float m4 = (t >= 36) ? mloc : 0.f;
    #pragma unroll
    for (int o = 32; o > 0; o >>= 1) m4 = fmaxf(m4, __shfl_xor(m4, o));
    float inv4 = (m4 > 0.f) ? 7.f / m4 : 0.f;
    uint n0_ = (uint)(((int)rintf(v.x * inv4) + 8) & 0xF);
    uint n1_ = (uint)(((int)rintf(v.y * inv4) + 8) & 0xF);
    uint n2_ = (uint)(((int)rintf(v.z * inv4) + 8) & 0xF);
    uint n3_ = (uint)(((int)rintf(v.w * inv4) + 8) & 0xF);
    uint part;
    if (t & 1) part = (n0_ << 4) | (n1_ << 12) | (n2_ << 20) | (n3_ << 28);
    else       part =  n0_       | (n1_ << 8)  | (n2_ << 16) | (n3_ << 24);
    uint other = __shfl(part, t ^ 1);
    if (!(t & 1) && t >= 36) {
        uint u = part | other;
        int m = t >> 1;              // octet 18..31
        int cc = (m >> 1) - 9;       // chunk 0..6
        int pos = m & 1;
        wTq4[(((long)(dir * 7 + cc) * 1024 + j) << 1) + pos] = u;
    }
    if (t == 0) {
        swf[row]  = (mx > 0.f) ? (mx / 127.f) * (1.f / 127.f) : 0.f;
        swf4[row] = (m4 > 0.f) ? (m4 / 7.f)   * (1.f / 127.f) : 0.f;
    }
}

// ---------- w_ih1 per-row int8 quantize (K=512) ----------
__global__ void quant_wih1(const float* __restrict__ w, uint* __restrict__ wq,
                           float* __restrict__ swf) {
    const int row = blockIdx.x;        // 0..2047
    const int t = threadIdx.x;         // owns k = 8t..8t+7
    float4 a = *(const float4*)(w + (long)row * 512 + t * 8);
    float4 b = *(const float4*)(w + (long)row * 512 + t * 8 + 4);
    float mx = fmaxf(fmaxf(fmaxf(fabsf(a.x), fabsf(a.y)), fmaxf(fabsf(a.z), fabsf(a.w))),
                     fmaxf(fmaxf(fabsf(b.x), fabsf(b.y)), fmaxf(fabsf(b.z), fabsf(b.w))));
    #pragma unroll
    for (int o = 32; o > 0; o >>= 1) mx = fmaxf(mx, __shfl_xor(mx, o));
    float inv = (mx > 0.f) ? 127.f / mx : 0.f;
    uint q0 = (uint)((int)rintf(a.x * inv) & 255) | ((uint)((int)rintf(a.y * inv) & 255) << 8)
            | ((uint)((int)rintf(a.z * inv) & 255) << 16) | ((uint)((int)rintf(a.w * inv) & 255) << 24);
    uint q1 = (uint)((int)rintf(b.x * inv) & 255) | ((uint)((int)rintf(b.y * inv) & 255) << 8)
            | ((uint)((int)rintf(b.z * inv) & 255) << 16) | ((uint)((int)rintf(b.w * inv) & 255) << 24);
    wq[(long)row * 128 + t * 2]     = q0;
    wq[(long)row * 128 + t * 2 + 1] = q1;
    if (t == 0) swf[row] = (mx > 0.f) ? mx / (127.f * 127.f) : 0.f;
}

// ---------- plain f16 pack ----------
__global__ void pack_f16(const float* __restrict__ in, ushort* __restrict__ out, int n8) {
    int i = blockIdx.x * 256 + threadIdx.x;
    if (i >= n8) return;
    float4 a = *(const float4*)(in + (long)i * 8);
    float4 b = *(const float4*)(in + (long)i * 8 + 4);
    _Float16 o[8] = {(_Float16)a.x, (_Float16)a.y, (_Float16)a.z, (_Float16)a.w,
                     (_Float16)b.x, (_Float16)b.y, (_Float16)b.z, (_Float16)b.w};
    *(uint4*)(out + (long)i * 8) = *(uint4*)o;
}

// ---------- f16 xg GEMM (layer 0, proven): BM=BN=128, 8x8 microtile ----------
template <int KDIM, bool GATHER>
__global__ __launch_bounds__(256, 2) void gemm_xg16b(
    const void* __restrict__ Av, const int* __restrict__ tokens,
    const ushort* __restrict__ Wh, const float* __restrict__ bias,
    float* __restrict__ out, int t_base, int t_sign)
{
    __shared__ uint4 As[2][144];
    __shared__ uint4 Bs[2][144];
    const int tid = threadIdx.x;
    const int m0 = blockIdx.x * 128;
    const int n0 = blockIdx.y * 128;

    const int lr  = tid & 127;
    const int lk8 = tid >> 7;
    const int tcc = (m0 + lr) & (TC - 1);
    const int b   = (m0 + lr) >> TCLOG;
    const int tglob = t_base + t_sign * tcc;
    const long arow = (long)b * SS + tglob;
    const float*  Af = GATHER ? ((const float*)Av + (long)tokens[arow] * KDIM + lk8 * 8) : nullptr;
    const ushort* Ah = GATHER ? nullptr : ((const ushort*)Av + arow * (long)KDIM + lk8 * 8);
    const ushort* Wp = Wh + (long)(n0 + lr) * KDIM + lk8 * 8;
    const int lpad = lr + (lr >> 3);

    const int tr = tid >> 4;
    const int tn = tid & 15;

    float acc[8][8];
    #pragma unroll
    for (int i = 0; i < 8; i++)
        #pragma unroll
        for (int j = 0; j < 8; j++) acc[i][j] = 0.f;

    #pragma unroll 1
    for (int k0 = 0; k0 < KDIM; k0 += 16) {
        uint4 aw, bw;
        if (GATHER) {
            float4 a0 = *(const float4*)(Af + k0);
            float4 a1 = *(const float4*)(Af + k0 + 4);
            aw.x = (uint)f16b(a0.x) | ((uint)f16b(a0.y) << 16);
            aw.y = (uint)f16b(a0.z) | ((uint)f16b(a0.w) << 16);
            aw.z = (uint)f16b(a1.x) | ((uint)f16b(a1.y) << 16);
            aw.w = (uint)f16b(a1.z) | ((uint)f16b(a1.w) << 16);
        } else {
            aw = *(const uint4*)(Ah + k0);
        }
        bw = *(const uint4*)(Wp + k0);
        As[lk8][lpad] = aw;
        Bs[lk8][lpad] = bw;
        __syncthreads();
        #pragma unroll
        for (int k8 = 0; k8 < 2; k8++) {
            uint4 a[8], w[8];
            #pragma unroll
            for (int i = 0; i < 8; i++) {
                a[i] = As[k8][tr * 9 + i];
                w[i] = Bs[k8][tn * 9 + i];
            }
            #pragma unroll
            for (int i = 0; i < 8; i++)
                #pragma unroll
                for (int j = 0; j < 8; j++)
                    acc[i][j] = dot8h(w[j], a[i], acc[i][j]);
        }
        __syncthreads();
    }

    float4 bc0 = *(const float4*)(bias + n0 + tn * 8);
    float4 bc1 = *(const float4*)(bias + n0 + tn * 8 + 4);
    #pragma unroll
    for (int i = 0; i < 8; i++) {
        float* op = out + (long)(m0 + tr * 8 + i) * G4 + n0 + tn * 8;
        float4 r0, r1;
        r0.x = acc[i][0] + bc0.x; r0.y = acc[i][1] + bc0.y;
        r0.z = acc[i][2] + bc0.z; r0.w = acc[i][3] + bc0.w;
        r1.x = acc[i][4] + bc1.x; r1.y = acc[i][5] + bc1.y;
        r1.z = acc[i][6] + bc1.z; r1.w = acc[i][7] + bc1.w;
        *(float4*)op = r0;
        *(float4*)(op + 4) = r1;
    }
}

// ---------- int8 xg GEMM (layer 1): A = H0 int8, W = w_ih1 int8, sdot4 ----------
__global__ __launch_bounds__(256, 2) void gemm_xg8(
    const unsigned char* __restrict__ A8,   // [B*S][512] int8 (h*127)
    const uint* __restrict__ Wq,            // per-dir [1024][128 uint]
    const float* __restrict__ swf,          // per-dir [1024] = maxw/(127*127)
    const float* __restrict__ bias,         // per-dir [1024]
    float* __restrict__ out,                // (B*TC, 1024)
    int t_base, int t_sign)
{
    __shared__ uint4 As[144];
    __shared__ uint4 Bs[144];
    const int tid = threadIdx.x;
    const int m0 = blockIdx.x * 128;
    const int n0 = blockIdx.y * 128;

    const int lr   = tid & 127;
    const int half = tid >> 7;
    const int tcc = (m0 + lr) & (TC - 1);
    const int b   = (m0 + lr) >> TCLOG;
    const int tglob = t_base + t_sign * tcc;
    const long arow = (long)b * SS + tglob;
    const uint4* Ap = (const uint4*)(A8 + arow * 512);
    const uint4* Wp = (const uint4*)Wq + (long)(n0 + lr) * 32;
    const int lpad = lr + (lr >> 3);

    const int tr = tid >> 4;
    const int tn = tid & 15;

    int acc[8][8];
    #pragma unroll
    for (int i = 0; i < 8; i++)
        #pragma unroll
        for (int j = 0; j < 8; j++) acc[i][j] = 0;

    #pragma unroll 1
    for (int k0 = 0; k0 < 32; k0++) {       // 32 x 16-k steps
        uint4 v = half ? Wp[k0] : Ap[k0];
        if (half) Bs[lpad] = v; else As[lpad] = v;
        __syncthreads();
        uint4 a[8], w[8];
        #pragma unroll
        for (int i = 0; i < 8; i++) {
            a[i] = As[tr * 9 + i];
            w[i] = Bs[tn * 9 + i];
        }
        #pragma unroll
        for (int i = 0; i < 8; i++)
            #pragma unroll
            for (int j = 0; j < 8; j++)
                acc[i][j] = dot16q(w[j], a[i], acc[i][j]);
        __syncthreads();
    }

    float s[8], bs[8];
    #pragma unroll
    for (int jj = 0; jj < 8; jj++) {
        s[jj]  = swf[n0 + tn * 8 + jj];
        bs[jj] = bias[n0 + tn * 8 + jj];
    }
    #pragma unroll
    for (int i = 0; i < 8; i++) {
        float r[8];
        #pragma unroll
        for (int jj = 0; jj < 8; jj++) r[jj] = fmaf((float)acc[i][jj], s[jj], bs[jj]);
        float* op = out + (long)(m0 + tr * 8 + i) * G4 + n0 + tn * 8;
        *(float4*)op       = make_float4(r[0], r[1], r[2], r[3]);
        *(float4*)(op + 4) = make_float4(r[4], r[5], r[6], r[7]);
    }
}

// ---------- int8-cached + int4-streamed LSTM scan ----------
// Round-16 structure (2 barriers, gl exchange). Streamed chunks 9..15 are int4
// bias-8: Sum((nib-8)*h) = Sum(nib*h) - 8*hsum, hsum (exact int) maintained in LDS.
__global__ __launch_bounds__(1024, 4) void lstm_qscan3(
    const float* __restrict__ xgF, const float* __restrict__ xgB,
    const uint* __restrict__ wTq,     // int8 [2][16][1024][4] (chunks 0..8 used)
    const uint* __restrict__ wTq4,    // int4 [2][7][1024][2]
    const float* __restrict__ swf,    // [2][1024]
    const float* __restrict__ swf4,   // [2][1024]
    const float* __restrict__ bhh2,   // [2][1024]
    ushort* __restrict__ hout,        // f16 H (layer 1)
    unsigned char* __restrict__ hout8,// int8 H (layer 0)
    int doW8,
    float* __restrict__ state,        // [2][B][2][256]
    int tbF, int tbB, int doInit)
{
    const int b = blockIdx.x;
    const int d = blockIdx.y;
    const int j = threadIdx.x;
    const float* xg = (d ? xgB : xgF) + (long)b * TC * G4 + j;
    const uint4* wTd = (const uint4*)wTq + (long)d * 16 * 1024;
    const uint2* w4d = (const uint2*)wTq4 + (long)d * 7 * 1024;

    __shared__ __align__(16) uint hq[2][64];
    __shared__ float gl[G4];
    __shared__ int hsum_l[2];
    __shared__ uint4 lwq[KLQ * 1024];

    #pragma unroll
    for (int kc = 0; kc < KLQ; kc++)
        lwq[kc * 1024 + j] = wTd[(long)kc * 1024 + j];

    const float bj = bhh2[d * G4 + j];
    const float s8 = swf[d * G4 + j];
    const float s4 = swf4[d * G4 + j];
    float c_reg = 0.f, h_reg = 0.f;
    if (j < HH && !doInit) {
        h_reg = state[((d * BB + b) * 2 + 0) * HH + j];
        c_reg = state[((d * BB + b) * 2 + 1) * HH + j];
    }
    int qh0 = __float2int_rn(h_reg * 127.f);
    if (j < HH) ((char*)hq[0])[j] = (char)qh0;
    if (j == 0) { hsum_l[0] = 0; hsum_l[1] = 0; }
    __syncthreads();
    if (j >= 128 && j < 256) {                 // initial hsum over k in [144,256)
        int v = (j >= 144) ? qh0 : 0;
        #pragma unroll
        for (int o = 32; o > 0; o >>= 1) v += __shfl_xor(v, o);
        if ((j & 63) == 0) atomicAdd(&hsum_l[0], v);
    }
    __syncthreads();

    #pragma unroll 1
    for (int tc = 0; tc < TC; ++tc) {
        const int rb = tc & 1;
        const uint4* hc = (const uint4*)hq[rb];
        int isum8 = 0;
        #pragma unroll
        for (int kc = 0; kc < KLQ; kc++)
            isum8 = dot16q(lwq[kc * 1024 + j], hc[kc], isum8);
        int isum4 = 0;
        #pragma unroll
        for (int cc = 0; cc < 7; cc++) {
            uint2 u = w4d[(long)cc * 1024 + j];
            uint4 h = hc[9 + cc];
            isum4 = __builtin_amdgcn_sdot4((int)(u.x & 0x0F0F0F0Fu),        (int)h.x, isum4, false);
            isum4 = __builtin_amdgcn_sdot4((int)((u.x >> 4) & 0x0F0F0F0Fu), (int)h.y, isum4, false);
            isum4 = __builtin_amdgcn_sdot4((int)(u.y & 0x0F0F0F0Fu),        (int)h.z, isum4, false);
            isum4 = __builtin_amdgcn_sdot4((int)((u.y >> 4) & 0x0F0F0F0Fu), (int)h.w, isum4, false);
        }
        const int hs = hsum_l[rb];
        gl[j] = fmaf(s4, (float)(isum4 - 8 * hs),
                 fmaf(s8, (float)isum8, xg[(long)tc * G4] + bj));
        if (j == 0) hsum_l[rb ^ 1] = 0;
        __syncthreads();
        int qh = 0;
        if (j < HH) {
            float gi = gl[j], gf = gl[j + 256], gg = gl[j + 512], go = gl[j + 768];
            c_reg = sigf(gf) * c_reg + sigf(gi) * tanhfast(gg);
            float h = sigf(go) * tanhfast(c_reg);
            h_reg = h;
            qh = __float2int_rn(h * 127.f);
            ((char*)hq[rb ^ 1])[j] = (char)qh;
            const int t = d ? (tbB - tc) : (tbF + tc);
            if (doW8) hout8[((long)(b * SS + t)) * 512 + d * HH + j] = (unsigned char)(char)qh;
            else      hout [((long)(b * SS + t)) * 512 + d * HH + j] = f16b(h);
        }
        if (j >= 128 && j < 256) {
            int v = (j >= 144) ? qh : 0;
            #pragma unroll
            for (int o = 32; o > 0; o >>= 1) v += __shfl_xor(v, o);
            if ((j & 63) == 0) atomicAdd(&hsum_l[rb ^ 1], v);
        }
        __syncthreads();
    }

    if (j < HH) {
        state[((d * BB + b) * 2 + 0) * HH + j] = h_reg;
        state[((d * BB + b) * 2 + 1) * HH + j] = c_reg;
    }
}

// ---------- emissions (f16 h) ----------
__global__ __launch_bounds__(256) void emissions_k16(
    const ushort* __restrict__ h1, const float* __restrict__ clsw,
    const float* __restrict__ clsb, float* __restrict__ em)
{
    long u = (long)blockIdx.x * 256 + threadIdx.x;
    if (u >= (long)BB * SS * NC) return;
    int c = (int)(u % NC);
    long m = u / NC;
    const uint* hr = (const uint*)(h1 + m * 512);
    const float2* wr = (const float2*)(clsw + (long)c * 512);
    float s0 = 0, s1 = 0;
    #pragma unroll 8
    for (int q = 0; q < 256; q += 2) {
        half2v h0 = __builtin_bit_cast(half2v, hr[q]);
        half2v h1v = __builtin_bit_cast(half2v, hr[q + 1]);
        float2 w0 = wr[q], w1 = wr[q + 1];
        s0 += (float)h0.x * w0.x + (float)h0.y * w0.y;
        s1 += (float)h1v.x * w1.x + (float)h1v.y * w1.y;
    }
    em[u] = s0 + s1 + clsb[c];
}

// ---------- CRF log-likelihood per batch row ----------
__global__ __launch_bounds__(64) void crf_llh(
    const float* __restrict__ em, const int* __restrict__ labels,
    const int* __restrict__ mask, const float* __restrict__ start,
    const float* __restrict__ endt, const float* __restrict__ trans,
    float* __restrict__ llh)
{
    int b = blockIdx.x, j = threadIdx.x;
    bool act = j < NC;
    float tcol[NC];
    #pragma unroll
    for (int i = 0; i < NC; i++) tcol[i] = act ? trans[i * NC + j] : 0.f;
    const float* emb_ = em + (long)b * SS * NC;
    const int* lb = labels + b * SS;
    const int* mk = mask + b * SS;
    float alpha = act ? (start[j] + emb_[j]) : -1e30f;

    float num = 0.f;
    int msum = 0;
    for (int t = j; t < SS; t += 64) msum += (mk[t] != 0);
    for (int t = 1 + j; t < SS; t += 64) {
        float m = (float)mk[t];
        num += m * (trans[lb[t - 1] * NC + lb[t]] + emb_[t * NC + lb[t]]);
    }
    for (int o = 32; o > 0; o >>= 1) {
        num  += __shfl_down(num, o);
        msum += __shfl_down(msum, o);
    }
    msum = __shfl(msum, 0);

    for (int t = 1; t < SS; t++) {
        int m = mk[t];
        float emj = act ? emb_[t * NC + j] : 0.f;
        float v[NC];
        float mx = -1e30f;
        #pragma unroll
        for (int i = 0; i < NC; i++) {
            v[i] = __shfl(alpha, i) + tcol[i];
            mx = fmaxf(mx, v[i]);
        }
        float sum = 0.f;
        #pragma unroll
        for (int i = 0; i < NC; i++) sum += __expf(v[i] - mx);
        float nxt = mx + __logf(sum) + emj;
        if (m > 0 && act) alpha = nxt;
    }
    float fin = act ? alpha + endt[j] : -1e30f;
    float mx = -1e30f;
    #pragma unroll
    for (int i = 0; i < NC; i++) mx = fmaxf(mx, __shfl(fin, i));
    float s = 0.f;
    #pragma unroll
    for (int i = 0; i < NC; i++) s += __expf(__shfl(fin, i) - mx);
    float den = mx + __logf(s);
    if (j == 0) {
        int last_idx = msum - 1;
        float numer = num + start[lb[0]] + emb_[lb[0]] + endt[lb[last_idx]];
        llh[b] = numer - den;
    }
}

__global__ __launch_bounds__(64) void loss_k(const float* __restrict__ llh, float* __restrict__ out) {
    int j = threadIdx.x;
    float v = llh[j];
    for (int o = 32; o > 0; o >>= 1) v += __shfl_down(v, o);
    if (j == 0) out[0] = -v / 64.0f;
}

// ---------- Viterbi per batch row ----------
__global__ __launch_bounds__(64) void viterbi_k(
    const float* __restrict__ em, const int* __restrict__ mask,
    const float* __restrict__ start, const float* __restrict__ endt,
    const float* __restrict__ trans, float* __restrict__ outp)
{
    int b = blockIdx.x, j = threadIdx.x;
    bool act = j < NC;
    __shared__ unsigned char bp[SS][NC];
    float tcol[NC];
    #pragma unroll
    for (int i = 0; i < NC; i++) tcol[i] = act ? trans[i * NC + j] : 0.f;
    const float* emb_ = em + (long)b * SS * NC;
    const int* mk = mask + b * SS;
    float score = act ? (start[j] + emb_[j]) : -1e30f;

    for (int t = 1; t < SS; t++) {
        float best = 0.f;
        int bi = 0;
        #pragma unroll
        for (int i = 0; i < NC; i++) {
            float vv = __shfl(score, i) + tcol[i];
            if (i == 0 || vv > best) { best = vv; bi = i; }   // first-max (jnp.argmax)
        }
        int m = mk[t];
        float nxt = best + (act ? emb_[t * NC + j] : 0.f);
        if (act) {
            if (m > 0) { score = nxt; bp[t][j] = (unsigned char)bi; }
            else       { bp[t][j] = (unsigned char)j; }
        }
    }
    float fin = act ? score + endt[j] : -1e30f;
    float bestf = 0.f;
    int last = 0;
    #pragma unroll
    for (int i = 0; i < NC; i++) {
        float vv = __shfl(fin, i);
        if (i == 0 || vv > bestf) { bestf = vv; last = i; }
    }
    __syncthreads();
    if (j == 0) {
        int cur = last;
        outp[1 + (long)b * SS + (SS - 1)] = (float)cur;
        for (int t = SS - 1; t >= 1; t--) {
            cur = bp[t][cur];
            outp[1 + (long)b * SS + (t - 1)] = (float)cur;
        }
    }
}

extern "C" void kernel_launch(void* const* d_in, const int* in_sizes, int n_in,
                              void* d_out, int out_size, void* d_ws, size_t ws_size,
                              hipStream_t stream) {
    const int*   tok    = (const int*)d_in[0];
    const int*   lab    = (const int*)d_in[1];
    const int*   msk    = (const int*)d_in[2];
    const float* emb    = (const float*)d_in[3];
    const float* w_ih0  = (const float*)d_in[4];   // (2,1024,128)
    const float* w_hh0  = (const float*)d_in[5];   // (2,1024,256)
    const float* b_ih0  = (const float*)d_in[6];
    const float* b_hh0  = (const float*)d_in[7];
    const float* w_ih1  = (const float*)d_in[8];   // (2,1024,512)
    const float* w_hh1  = (const float*)d_in[9];
    const float* b_ih1  = (const float*)d_in[10];
    const float* b_hh1  = (const float*)d_in[11];
    const float* clsw   = (const float*)d_in[12];
    const float* clsb   = (const float*)d_in[13];
    const float* startt = (const float*)d_in[14];
    const float* endt   = (const float*)d_in[15];
    const float* transm = (const float*)d_in[16];
    float* out = (float*)d_out;

    // ---- workspace carve (f32 element units); ~125 MB ----
    size_t nH8  = (size_t)BB * SS * 512 / 4;       // int8 H0
    size_t nHh  = (size_t)BB * SS * 512 / 2;       // f16 H1
    size_t nWQ  = (size_t)2 * 16 * 1024 * 4;       // whh int8 per layer (uints)
    size_t nW4  = (size_t)2 * 7 * 1024 * 2;        // whh int4 per layer (uints)
    size_t nSW  = (size_t)2 * 1024;
    size_t nWI0 = (size_t)2048 * 128 / 2;          // w_ih0 f16
    size_t nWQ1 = (size_t)2048 * 128;              // w_ih1 int8 (uints)
    size_t nEM  = (size_t)BB * SS * NC;
    size_t nST  = (size_t)2 * BB * 2 * HH;
    size_t nXG  = (size_t)BB * TC * G4;

    float* H08f = (float*)d_ws;
    float* H1f  = H08f + nH8;
    float* WQ0  = H1f + nHh;
    float* WQ1w = WQ0 + nWQ;
    float* W40  = WQ1w + nWQ;
    float* W41  = W40 + nW4;
    float* SW0  = W41 + nW4;
    float* SW1  = SW0 + nSW;
    float* S40  = SW1 + nSW;
    float* S41  = S40 + nSW;
    float* WI0  = S41 + nSW;
    float* WQI1 = WI0 + nWI0;
    float* SWI1 = WQI1 + nWQ1;
    float* EM   = SWI1 + 2048;
    float* ST   = EM + nEM;
    float* LLH  = ST + nST;
    float* XGF  = LLH + 64;
    float* XGB  = XGF + nXG;

    unsigned char* H08 = (unsigned char*)H08f;
    ushort* H1h  = (ushort*)H1f;
    ushort* WI0h = (ushort*)WI0;

    quant_whh<<<2048, 64, 0, stream>>>(w_hh0, (uint*)WQ0, (uint*)W40, SW0, S40);
    quant_whh<<<2048, 64, 0, stream>>>(w_hh1, (uint*)WQ1w, (uint*)W41, SW1, S41);
    quant_wih1<<<2048, 64, 0, stream>>>(w_ih1, (uint*)WQI1, SWI1);
    pack_f16<<<(2048 * 128 / 8 + 255) / 256, 256, 0, stream>>>(w_ih0, WI0h, 2048 * 128 / 8);

    dim3 gg2((BB * TC) / 128, G4 / 128);  // (64, 8)
    dim3 rg(BB, 2);                       // 128 blocks, 1024 threads

    // ---- layer 0 (f16 gemm, scan emits int8 H0) ----
    for (int c = 0; c < NCH; c++) {
        int tbF = c * TC;
        int tbB = SS - 1 - c * TC;
        gemm_xg16b<128, true><<<gg2, 256, 0, stream>>>(emb, tok, WI0h,              b_ih0,        XGF, tbF, +1);
        gemm_xg16b<128, true><<<gg2, 256, 0, stream>>>(emb, tok, WI0h + 1024 * 128, b_ih0 + 1024, XGB, tbB, -1);
        lstm_qscan3<<<rg, 1024, 0, stream>>>(XGF, XGB, (const uint*)WQ0, (const uint*)W40,
                                             SW0, S40, b_hh0, H1h, H08, 1, ST, tbF, tbB, c == 0);
    }
    // ---- layer 1 (int8 gemm from H08, scan emits f16 H1) ----
    for (int c = 0; c < NCH; c++) {
        int tbF = c * TC;
        int tbB = SS - 1 - c * TC;
        gemm_xg8<<<gg2, 256, 0, stream>>>(H08, (const uint*)WQI1,              SWI1,        b_ih1,        XGF, tbF, +1);
        gemm_xg8<<<gg2, 256, 0, stream>>>(H08, (const uint*)WQI1 + 1024 * 128, SWI1 + 1024, b_ih1 + 1024, XGB, tbB, -1);
        lstm_qscan3<<<rg, 1024, 0, stream>>>(XGF, XGB, (const uint*)WQ1w, (const uint*)W41,
                                             SW1, S41, b_hh1, H1h, H08, 0, ST, tbF, tbB, c == 0);
    }

    emissions_k16<<<((BB * SS * NC) + 255) / 256, 256, 0, stream>>>(H1h, clsw, clsb, EM);
    crf_llh<<<BB, 64, 0, stream>>>(EM, lab, msk, startt, endt, transm, LLH);
    loss_k<<<1, 64, 0, stream>>>(LLH, out);
    viterbi_k<<<BB, 64, 0, stream>>>(EM, msk, startt, endt, transm, out);
}

// Round 20
// 2249.443 us; speedup vs baseline: 1.1683x; 1.1683x over previous
//
#include <hip/hip_runtime.h>
#include <math.h>

#define BB 64      // batch
#define SS 512     // seq len
#define EE 128     // embed dim
#define HH 256     // hidden
#define NC 9       // classes
#define G4 1024    // 4*H gates (one direction)
#define TCLOG 7
#define TC 128     // time chunk
#define NCH (SS / TC)

#define KLQ 9      // int8 k16 chunks cached in LDS = 144 KB; 7 streamed int8

typedef _Float16 half2v __attribute__((ext_vector_type(2)));

// ---------- activations ----------
__device__ __forceinline__ float sigf(float x) {
    return 1.0f / (1.0f + __expf(-x));
}
__device__ __forceinline__ float tanhfast(float x) {
    float a = fabsf(x);
    float e = __expf(-2.0f * a);
    float t = (1.0f - e) / (1.0f + e);
    return copysignf(t, x);
}
__device__ __forceinline__ float dot8h(uint4 w, uint4 h, float acc) {
    acc = __builtin_amdgcn_fdot2(__builtin_bit_cast(half2v, w.x),
                                 __builtin_bit_cast(half2v, h.x), acc, false);
    acc = __builtin_amdgcn_fdot2(__builtin_bit_cast(half2v, w.y),
                                 __builtin_bit_cast(half2v, h.y), acc, false);
    acc = __builtin_amdgcn_fdot2(__builtin_bit_cast(half2v, w.z),
                                 __builtin_bit_cast(half2v, h.z), acc, false);
    acc = __builtin_amdgcn_fdot2(__builtin_bit_cast(half2v, w.w),
                                 __builtin_bit_cast(half2v, h.w), acc, false);
    return acc;
}
__device__ __forceinline__ int dot16q(uint4 w, uint4 h, int acc) {
    acc = __builtin_amdgcn_sdot4((int)w.x, (int)h.x, acc, false);
    acc = __builtin_amdgcn_sdot4((int)w.y, (int)h.y, acc, false);
    acc = __builtin_amdgcn_sdot4((int)w.z, (int)h.z, acc, false);
    acc = __builtin_amdgcn_sdot4((int)w.w, (int)h.w, acc, false);
    return acc;
}
__device__ __forceinline__ ushort f16b(float x) {
    return __builtin_bit_cast(ushort, (_Float16)x);
}

// ---------- per-row int8 quantize + transpose: w_hh -> wTq[dir][kc][j][16 i8] ----------
__global__ void quant_whh(const float* __restrict__ whh, uint* __restrict__ wTq,
                          float* __restrict__ swf) {
    const int row = blockIdx.x;        // 0..2047
    const int t = threadIdx.x;         // 0..63, owns k = 4t..4t+3
    float4 v = *(const float4*)(whh + (long)row * 256 + t * 4);
    float mx = fmaxf(fmaxf(fabsf(v.x), fabsf(v.y)), fmaxf(fabsf(v.z), fabsf(v.w)));
    #pragma unroll
    for (int o = 32; o > 0; o >>= 1) mx = fmaxf(mx, __shfl_xor(mx, o));
    float inv = (mx > 0.f) ? 127.f / mx : 0.f;
    int q0 = (int)rintf(v.x * inv) & 255;
    int q1 = (int)rintf(v.y * inv) & 255;
    int q2 = (int)rintf(v.z * inv) & 255;
    int q3 = (int)rintf(v.w * inv) & 255;
    uint u = (uint)q0 | ((uint)q1 << 8) | ((uint)q2 << 16) | ((uint)q3 << 24);
    const int dir = row >> 10, j = row & 1023;
    const int kc = t >> 2, l4 = t & 3;
    wTq[(((long)(dir * 16 + kc) * 1024 + j) << 2) + l4] = u;
    if (t == 0) swf[row] = (mx > 0.f) ? (mx / 127.f) * (1.f / 127.f) : 0.f;  // s_w * s_h
}

// ---------- w_ih1 per-row int8 quantize (K=512) ----------
__global__ void quant_wih1(const float* __restrict__ w, uint* __restrict__ wq,
                           float* __restrict__ swf) {
    const int row = blockIdx.x;        // 0..2047
    const int t = threadIdx.x;         // owns k = 8t..8t+7
    float4 a = *(const float4*)(w + (long)row * 512 + t * 8);
    float4 b = *(const float4*)(w + (long)row * 512 + t * 8 + 4);
    float mx = fmaxf(fmaxf(fmaxf(fabsf(a.x), fabsf(a.y)), fmaxf(fabsf(a.z), fabsf(a.w))),
                     fmaxf(fmaxf(fabsf(b.x), fabsf(b.y)), fmaxf(fabsf(b.z), fabsf(b.w))));
    #pragma unroll
    for (int o = 32; o > 0; o >>= 1) mx = fmaxf(mx, __shfl_xor(mx, o));
    float inv = (mx > 0.f) ? 127.f / mx : 0.f;
    uint q0 = (uint)((int)rintf(a.x * inv) & 255) | ((uint)((int)rintf(a.y * inv) & 255) << 8)
            | ((uint)((int)rintf(a.z * inv) & 255) << 16) | ((uint)((int)rintf(a.w * inv) & 255) << 24);
    uint q1 = (uint)((int)rintf(b.x * inv) & 255) | ((uint)((int)rintf(b.y * inv) & 255) << 8)
            | ((uint)((int)rintf(b.z * inv) & 255) << 16) | ((uint)((int)rintf(b.w * inv) & 255) << 24);
    wq[(long)row * 128 + t * 2]     = q0;
    wq[(long)row * 128 + t * 2 + 1] = q1;
    if (t == 0) swf[row] = (mx > 0.f) ? mx / (127.f * 127.f) : 0.f;
}

// ---------- plain f16 pack ----------
__global__ void pack_f16(const float* __restrict__ in, ushort* __restrict__ out, int n8) {
    int i = blockIdx.x * 256 + threadIdx.x;
    if (i >= n8) return;
    float4 a = *(const float4*)(in + (long)i * 8);
    float4 b = *(const float4*)(in + (long)i * 8 + 4);
    _Float16 o[8] = {(_Float16)a.x, (_Float16)a.y, (_Float16)a.z, (_Float16)a.w,
                     (_Float16)b.x, (_Float16)b.y, (_Float16)b.z, (_Float16)b.w};
    *(uint4*)(out + (long)i * 8) = *(uint4*)o;
}

// ---------- f16 xg GEMM (layer 0, proven): BM=BN=128, 8x8 microtile ----------
template <int KDIM, bool GATHER>
__global__ __launch_bounds__(256, 2) void gemm_xg16b(
    const void* __restrict__ Av, const int* __restrict__ tokens,
    const ushort* __restrict__ Wh, const float* __restrict__ bias,
    float* __restrict__ out, int t_base, int t_sign)
{
    __shared__ uint4 As[2][144];
    __shared__ uint4 Bs[2][144];
    const int tid = threadIdx.x;
    const int m0 = blockIdx.x * 128;
    const int n0 = blockIdx.y * 128;

    const int lr  = tid & 127;
    const int lk8 = tid >> 7;
    const int tcc = (m0 + lr) & (TC - 1);
    const int b   = (m0 + lr) >> TCLOG;
    const int tglob = t_base + t_sign * tcc;
    const long arow = (long)b * SS + tglob;
    const float*  Af = GATHER ? ((const float*)Av + (long)tokens[arow] * KDIM + lk8 * 8) : nullptr;
    const ushort* Ah = GATHER ? nullptr : ((const ushort*)Av + arow * (long)KDIM + lk8 * 8);
    const ushort* Wp = Wh + (long)(n0 + lr) * KDIM + lk8 * 8;
    const int lpad = lr + (lr >> 3);

    const int tr = tid >> 4;
    const int tn = tid & 15;

    float acc[8][8];
    #pragma unroll
    for (int i = 0; i < 8; i++)
        #pragma unroll
        for (int j = 0; j < 8; j++) acc[i][j] = 0.f;

    #pragma unroll 1
    for (int k0 = 0; k0 < KDIM; k0 += 16) {
        uint4 aw, bw;
        if (GATHER) {
            float4 a0 = *(const float4*)(Af + k0);
            float4 a1 = *(const float4*)(Af + k0 + 4);
            aw.x = (uint)f16b(a0.x) | ((uint)f16b(a0.y) << 16);
            aw.y = (uint)f16b(a0.z) | ((uint)f16b(a0.w) << 16);
            aw.z = (uint)f16b(a1.x) | ((uint)f16b(a1.y) << 16);
            aw.w = (uint)f16b(a1.z) | ((uint)f16b(a1.w) << 16);
        } else {
            aw = *(const uint4*)(Ah + k0);
        }
        bw = *(const uint4*)(Wp + k0);
        As[lk8][lpad] = aw;
        Bs[lk8][lpad] = bw;
        __syncthreads();
        #pragma unroll
        for (int k8 = 0; k8 < 2; k8++) {
            uint4 a[8], w[8];
            #pragma unroll
            for (int i = 0; i < 8; i++) {
                a[i] = As[k8][tr * 9 + i];
                w[i] = Bs[k8][tn * 9 + i];
            }
            #pragma unroll
            for (int i = 0; i < 8; i++)
                #pragma unroll
                for (int j = 0; j < 8; j++)
                    acc[i][j] = dot8h(w[j], a[i], acc[i][j]);
        }
        __syncthreads();
    }

    float4 bc0 = *(const float4*)(bias + n0 + tn * 8);
    float4 bc1 = *(const float4*)(bias + n0 + tn * 8 + 4);
    #pragma unroll
    for (int i = 0; i < 8; i++) {
        float* op = out + (long)(m0 + tr * 8 + i) * G4 + n0 + tn * 8;
        float4 r0, r1;
        r0.x = acc[i][0] + bc0.x; r0.y = acc[i][1] + bc0.y;
        r0.z = acc[i][2] + bc0.z; r0.w = acc[i][3] + bc0.w;
        r1.x = acc[i][4] + bc1.x; r1.y = acc[i][5] + bc1.y;
        r1.z = acc[i][6] + bc1.z; r1.w = acc[i][7] + bc1.w;
        *(float4*)op = r0;
        *(float4*)(op + 4) = r1;
    }
}

// ---------- int8 xg GEMM (layer 1, round-19 winner): A = H0 int8, sdot4 ----------
__global__ __launch_bounds__(256, 2) void gemm_xg8(
    const unsigned char* __restrict__ A8,   // [B*S][512] int8 (h*127)
    const uint* __restrict__ Wq,            // per-dir [1024][128 uint]
    const float* __restrict__ swf,          // per-dir [1024] = maxw/(127*127)
    const float* __restrict__ bias,         // per-dir [1024]
    float* __restrict__ out,                // (B*TC, 1024)
    int t_base, int t_sign)
{
    __shared__ uint4 As[144];
    __shared__ uint4 Bs[144];
    const int tid = threadIdx.x;
    const int m0 = blockIdx.x * 128;
    const int n0 = blockIdx.y * 128;

    const int lr   = tid & 127;
    const int half = tid >> 7;
    const int tcc = (m0 + lr) & (TC - 1);
    const int b   = (m0 + lr) >> TCLOG;
    const int tglob = t_base + t_sign * tcc;
    const long arow = (long)b * SS + tglob;
    const uint4* Ap = (const uint4*)(A8 + arow * 512);
    const uint4* Wp = (const uint4*)Wq + (long)(n0 + lr) * 32;
    const int lpad = lr + (lr >> 3);

    const int tr = tid >> 4;
    const int tn = tid & 15;

    int acc[8][8];
    #pragma unroll
    for (int i = 0; i < 8; i++)
        #pragma unroll
        for (int j = 0; j < 8; j++) acc[i][j] = 0;

    #pragma unroll 1
    for (int k0 = 0; k0 < 32; k0++) {       // 32 x 16-k steps
        uint4 v = half ? Wp[k0] : Ap[k0];
        if (half) Bs[lpad] = v; else As[lpad] = v;
        __syncthreads();
        uint4 a[8], w[8];
        #pragma unroll
        for (int i = 0; i < 8; i++) {
            a[i] = As[tr * 9 + i];
            w[i] = Bs[tn * 9 + i];
        }
        #pragma unroll
        for (int i = 0; i < 8; i++)
            #pragma unroll
            for (int j = 0; j < 8; j++)
                acc[i][j] = dot16q(w[j], a[i], acc[i][j]);
        __syncthreads();
    }

    float s[8], bs[8];
    #pragma unroll
    for (int jj = 0; jj < 8; jj++) {
        s[jj]  = swf[n0 + tn * 8 + jj];
        bs[jj] = bias[n0 + tn * 8 + jj];
    }
    #pragma unroll
    for (int i = 0; i < 8; i++) {
        float r[8];
        #pragma unroll
        for (int jj = 0; jj < 8; jj++) r[jj] = fmaf((float)acc[i][jj], s[jj], bs[jj]);
        float* op = out + (long)(m0 + tr * 8 + i) * G4 + n0 + tn * 8;
        *(float4*)op       = make_float4(r[0], r[1], r[2], r[3]);
        *(float4*)(op + 4) = make_float4(r[4], r[5], r[6], r[7]);
    }
}

// ---------- int8-dot LSTM scan (round-18 proven) + doW8 hout selector ----------
__global__ __launch_bounds__(1024, 4) void lstm_qscan(
    const float* __restrict__ xgF, const float* __restrict__ xgB, // [B][TC][1024]
    const uint* __restrict__ wTq,     // [2][16][1024][4 uint]
    const float* __restrict__ swf,    // [2][1024] combined scale s_w*s_h
    const float* __restrict__ bhh2,   // [2][1024]
    ushort* __restrict__ hout,        // f16 H (layer 1)
    unsigned char* __restrict__ hout8,// int8 H (layer 0)
    int doW8,
    float* __restrict__ state,        // [2][B][2][256]
    int tbF, int tbB, int doInit)
{
    const int b = blockIdx.x;
    const int d = blockIdx.y;
    const int j = threadIdx.x;
    const float* xg = (d ? xgB : xgF) + (long)b * TC * G4 + j;
    const uint4* wTd = (const uint4*)wTq + (long)d * 16 * 1024;

    __shared__ __align__(16) uint hq[2][64];   // int8 h packed, 256 B each
    __shared__ float gl[G4];                   // 4 KB gate exchange
    __shared__ uint4 lwq[KLQ * 1024];          // 144 KB int8 weight cache

    #pragma unroll
    for (int kc = 0; kc < KLQ; kc++)
        lwq[kc * 1024 + j] = wTd[(long)kc * 1024 + j];

    const float bj  = bhh2[d * G4 + j];
    const float scl = swf[d * G4 + j];
    float c_reg = 0.f, h_reg = 0.f;
    if (j < HH) {
        if (!doInit) {
            h_reg = state[((d * BB + b) * 2 + 0) * HH + j];
            c_reg = state[((d * BB + b) * 2 + 1) * HH + j];
        }
        ((char*)hq[0])[j] = (char)__float2int_rn(h_reg * 127.f);
    }
    __syncthreads();   // covers hq init + lwq fill

    #pragma unroll 1
    for (int tc = 0; tc < TC; ++tc) {
        const int rb = tc & 1;
        const uint4* hc = (const uint4*)hq[rb];   // 16 x uint4 (broadcast)
        int isum = 0;

        #pragma unroll
        for (int kc = 0; kc < KLQ; kc++)
            isum = dot16q(lwq[kc * 1024 + j], hc[kc], isum);
        #pragma unroll
        for (int kc = KLQ; kc < 16; kc++)
            isum = dot16q(wTd[(long)kc * 1024 + j], hc[kc], isum);

        gl[j] = fmaf((float)isum, scl, xg[(long)tc * G4] + bj);
        __syncthreads();
        if (j < HH) {
            float gi = gl[j], gf = gl[j + 256], gg = gl[j + 512], go = gl[j + 768];
            c_reg = sigf(gf) * c_reg + sigf(gi) * tanhfast(gg);
            float h = sigf(go) * tanhfast(c_reg);
            h_reg = h;
            int qh = __float2int_rn(h * 127.f);
            ((char*)hq[rb ^ 1])[j] = (char)qh;
            const int t = d ? (tbB - tc) : (tbF + tc);
            if (doW8) hout8[((long)(b * SS + t)) * 512 + d * HH + j] = (unsigned char)(char)qh;
            else      hout [((long)(b * SS + t)) * 512 + d * HH + j] = f16b(h);
        }
        __syncthreads();
    }

    if (j < HH) {
        state[((d * BB + b) * 2 + 0) * HH + j] = h_reg;
        state[((d * BB + b) * 2 + 1) * HH + j] = c_reg;
    }
}

// ---------- emissions (f16 h) ----------
__global__ __launch_bounds__(256) void emissions_k16(
    const ushort* __restrict__ h1, const float* __restrict__ clsw,
    const float* __restrict__ clsb, float* __restrict__ em)
{
    long u = (long)blockIdx.x * 256 + threadIdx.x;
    if (u >= (long)BB * SS * NC) return;
    int c = (int)(u % NC);
    long m = u / NC;
    const uint* hr = (const uint*)(h1 + m * 512);
    const float2* wr = (const float2*)(clsw + (long)c * 512);
    float s0 = 0, s1 = 0;
    #pragma unroll 8
    for (int q = 0; q < 256; q += 2) {
        half2v h0 = __builtin_bit_cast(half2v, hr[q]);
        half2v h1v = __builtin_bit_cast(half2v, hr[q + 1]);
        float2 w0 = wr[q], w1 = wr[q + 1];
        s0 += (float)h0.x * w0.x + (float)h0.y * w0.y;
        s1 += (float)h1v.x * w1.x + (float)h1v.y * w1.y;
    }
    em[u] = s0 + s1 + clsb[c];
}

// ---------- CRF log-likelihood per batch row ----------
__global__ __launch_bounds__(64) void crf_llh(
    const float* __restrict__ em, const int* __restrict__ labels,
    const int* __restrict__ mask, const float* __restrict__ start,
    const float* __restrict__ endt, const float* __restrict__ trans,
    float* __restrict__ llh)
{
    int b = blockIdx.x, j = threadIdx.x;
    bool act = j < NC;
    float tcol[NC];
    #pragma unroll
    for (int i = 0; i < NC; i++) tcol[i] = act ? trans[i * NC + j] : 0.f;
    const float* emb_ = em + (long)b * SS * NC;
    const int* lb = labels + b * SS;
    const int* mk = mask + b * SS;
    float alpha = act ? (start[j] + emb_[j]) : -1e30f;

    float num = 0.f;
    int msum = 0;
    for (int t = j; t < SS; t += 64) msum += (mk[t] != 0);
    for (int t = 1 + j; t < SS; t += 64) {
        float m = (float)mk[t];
        num += m * (trans[lb[t - 1] * NC + lb[t]] + emb_[t * NC + lb[t]]);
    }
    for (int o = 32; o > 0; o >>= 1) {
        num  += __shfl_down(num, o);
        msum += __shfl_down(msum, o);
    }
    msum = __shfl(msum, 0);

    for (int t = 1; t < SS; t++) {
        int m = mk[t];
        float emj = act ? emb_[t * NC + j] : 0.f;
        float v[NC];
        float mx = -1e30f;
        #pragma unroll
        for (int i = 0; i < NC; i++) {
            v[i] = __shfl(alpha, i) + tcol[i];
            mx = fmaxf(mx, v[i]);
        }
        float sum = 0.f;
        #pragma unroll
        for (int i = 0; i < NC; i++) sum += __expf(v[i] - mx);
        float nxt = mx + __logf(sum) + emj;
        if (m > 0 && act) alpha = nxt;
    }
    float fin = act ? alpha + endt[j] : -1e30f;
    float mx = -1e30f;
    #pragma unroll
    for (int i = 0; i < NC; i++) mx = fmaxf(mx, __shfl(fin, i));
    float s = 0.f;
    #pragma unroll
    for (int i = 0; i < NC; i++) s += __expf(__shfl(fin, i) - mx);
    float den = mx + __logf(s);
    if (j == 0) {
        int last_idx = msum - 1;
        float numer = num + start[lb[0]] + emb_[lb[0]] + endt[lb[last_idx]];
        llh[b] = numer - den;
    }
}

__global__ __launch_bounds__(64) void loss_k(const float* __restrict__ llh, float* __restrict__ out) {
    int j = threadIdx.x;
    float v = llh[j];
    for (int o = 32; o > 0; o >>= 1) v += __shfl_down(v, o);
    if (j == 0) out[0] = -v / 64.0f;
}

// ---------- Viterbi per batch row ----------
__global__ __launch_bounds__(64) void viterbi_k(
    const float* __restrict__ em, const int* __restrict__ mask,
    const float* __restrict__ start, const float* __restrict__ endt,
    const float* __restrict__ trans, float* __restrict__ outp)
{
    int b = blockIdx.x, j = threadIdx.x;
    bool act = j < NC;
    __shared__ unsigned char bp[SS][NC];
    float tcol[NC];
    #pragma unroll
    for (int i = 0; i < NC; i++) tcol[i] = act ? trans[i * NC + j] : 0.f;
    const float* emb_ = em + (long)b * SS * NC;
    const int* mk = mask + b * SS;
    float score = act ? (start[j] + emb_[j]) : -1e30f;

    for (int t = 1; t < SS; t++) {
        float best = 0.f;
        int bi = 0;
        #pragma unroll
        for (int i = 0; i < NC; i++) {
            float vv = __shfl(score, i) + tcol[i];
            if (i == 0 || vv > best) { best = vv; bi = i; }   // first-max (jnp.argmax)
        }
        int m = mk[t];
        float nxt = best + (act ? emb_[t * NC + j] : 0.f);
        if (act) {
            if (m > 0) { score = nxt; bp[t][j] = (unsigned char)bi; }
            else       { bp[t][j] = (unsigned char)j; }
        }
    }
    float fin = act ? score + endt[j] : -1e30f;
    float bestf = 0.f;
    int last = 0;
    #pragma unroll
    for (int i = 0; i < NC; i++) {
        float vv = __shfl(fin, i);
        if (i == 0 || vv > bestf) { bestf = vv; last = i; }
    }
    __syncthreads();
    if (j == 0) {
        int cur = last;
        outp[1 + (long)b * SS + (SS - 1)] = (float)cur;
        for (int t = SS - 1; t >= 1; t--) {
            cur = bp[t][cur];
            outp[1 + (long)b * SS + (t - 1)] = (float)cur;
        }
    }
}

extern "C" void kernel_launch(void* const* d_in, const int* in_sizes, int n_in,
                              void* d_out, int out_size, void* d_ws, size_t ws_size,
                              hipStream_t stream) {
    const int*   tok    = (const int*)d_in[0];
    const int*   lab    = (const int*)d_in[1];
    const int*   msk    = (const int*)d_in[2];
    const float* emb    = (const float*)d_in[3];
    const float* w_ih0  = (const float*)d_in[4];   // (2,1024,128)
    const float* w_hh0  = (const float*)d_in[5];   // (2,1024,256)
    const float* b_ih0  = (const float*)d_in[6];
    const float* b_hh0  = (const float*)d_in[7];
    const float* w_ih1  = (const float*)d_in[8];   // (2,1024,512)
    const float* w_hh1  = (const float*)d_in[9];
    const float* b_ih1  = (const float*)d_in[10];
    const float* b_hh1  = (const float*)d_in[11];
    const float* clsw   = (const float*)d_in[12];
    const float* clsb   = (const float*)d_in[13];
    const float* startt = (const float*)d_in[14];
    const float* endt   = (const float*)d_in[15];
    const float* transm = (const float*)d_in[16];
    float* out = (float*)d_out;

    // ---- workspace carve (f32 element units); ~125 MB ----
    size_t nH8  = (size_t)BB * SS * 512 / 4;       // int8 H0
    size_t nHh  = (size_t)BB * SS * 512 / 2;       // f16 H1
    size_t nWQ  = (size_t)2 * 16 * 1024 * 4;       // whh int8 per layer (uints)
    size_t nSW  = (size_t)2 * 1024;
    size_t nWI0 = (size_t)2048 * 128 / 2;          // w_ih0 f16
    size_t nWQ1 = (size_t)2048 * 128;              // w_ih1 int8 (uints)
    size_t nEM  = (size_t)BB * SS * NC;
    size_t nST  = (size_t)2 * BB * 2 * HH;
    size_t nXG  = (size_t)BB * TC * G4;

    float* H08f = (float*)d_ws;
    float* H1f  = H08f + nH8;
    float* WQ0  = H1f + nHh;
    float* WQ1w = WQ0 + nWQ;
    float* SW0  = WQ1w + nWQ;
    float* SW1  = SW0 + nSW;
    float* WI0  = SW1 + nSW;
    float* WQI1 = WI0 + nWI0;
    float* SWI1 = WQI1 + nWQ1;
    float* EM   = SWI1 + 2048;
    float* ST   = EM + nEM;
    float* LLH  = ST + nST;
    float* XGF  = LLH + 64;
    float* XGB  = XGF + nXG;

    unsigned char* H08 = (unsigned char*)H08f;
    ushort* H1h  = (ushort*)H1f;
    ushort* WI0h = (ushort*)WI0;

    quant_whh<<<2048, 64, 0, stream>>>(w_hh0, (uint*)WQ0, SW0);
    quant_whh<<<2048, 64, 0, stream>>>(w_hh1, (uint*)WQ1w, SW1);
    quant_wih1<<<2048, 64, 0, stream>>>(w_ih1, (uint*)WQI1, SWI1);
    pack_f16<<<(2048 * 128 / 8 + 255) / 256, 256, 0, stream>>>(w_ih0, WI0h, 2048 * 128 / 8);

    dim3 gg2((BB * TC) / 128, G4 / 128);  // (64, 8)
    dim3 rg(BB, 2);                       // 128 blocks, 1024 threads

    // ---- layer 0 (f16 gemm, scan emits int8 H0) ----
    for (int c = 0; c < NCH; c++) {
        int tbF = c * TC;
        int tbB = SS - 1 - c * TC;
        gemm_xg16b<128, true><<<gg2, 256, 0, stream>>>(emb, tok, WI0h,              b_ih0,        XGF, tbF, +1);
        gemm_xg16b<128, true><<<gg2, 256, 0, stream>>>(emb, tok, WI0h + 1024 * 128, b_ih0 + 1024, XGB, tbB, -1);
        lstm_qscan<<<rg, 1024, 0, stream>>>(XGF, XGB, (const uint*)WQ0, SW0, b_hh0,
                                            H1h, H08, 1, ST, tbF, tbB, c == 0);
    }
    // ---- layer 1 (int8 gemm from H08, scan emits f16 H1) ----
    for (int c = 0; c < NCH; c++) {
        int tbF = c * TC;
        int tbB = SS - 1 - c * TC;
        gemm_xg8<<<gg2, 256, 0, stream>>>(H08, (const uint*)WQI1,              SWI1,        b_ih1,        XGF, tbF, +1);
        gemm_xg8<<<gg2, 256, 0, stream>>>(H08, (const uint*)WQI1 + 1024 * 128, SWI1 + 1024, b_ih1 + 1024, XGB, tbB, -1);
        lstm_qscan<<<rg, 1024, 0, stream>>>(XGF, XGB, (const uint*)WQ1w, SW1, b_hh1,
                                            H1h, H08, 0, ST, tbF, tbB, c == 0);
    }

    emissions_k16<<<((BB * SS * NC) + 255) / 256, 256, 0, stream>>>(H1h, clsw, clsb, EM);
    crf_llh<<<BB, 64, 0, stream>>>(EM, lab, msk, startt, endt, transm, LLH);
    loss_k<<<1, 64, 0, stream>>>(LLH, out);
    viterbi_k<<<BB, 64, 0, stream>>>(EM, msk, startt, endt, transm, out);
}

// Round 21
// 2195.056 us; speedup vs baseline: 1.1972x; 1.0248x over previous
//
#include <hip/hip_runtime.h>
#include <math.h>

#define BB 64      // batch
#define SS 512     // seq len
#define HH 256     // hidden
#define NC 9       // classes
#define G4 1024    // 4*H gates (one direction)
#define TCLOG 7
#define TC 128     // time chunk
#define NCH (SS / TC)

#define KLQ 9      // int8 k16 chunks cached in LDS = 144 KB; 7 streamed int8

typedef _Float16 half2v __attribute__((ext_vector_type(2)));

// ---------- activations ----------
__device__ __forceinline__ float sigf(float x) {
    return 1.0f / (1.0f + __expf(-x));
}
__device__ __forceinline__ float tanhfast(float x) {
    float a = fabsf(x);
    float e = __expf(-2.0f * a);
    float t = (1.0f - e) / (1.0f + e);
    return copysignf(t, x);
}
__device__ __forceinline__ float dot8h(uint4 w, uint4 h, float acc) {
    acc = __builtin_amdgcn_fdot2(__builtin_bit_cast(half2v, w.x),
                                 __builtin_bit_cast(half2v, h.x), acc, false);
    acc = __builtin_amdgcn_fdot2(__builtin_bit_cast(half2v, w.y),
                                 __builtin_bit_cast(half2v, h.y), acc, false);
    acc = __builtin_amdgcn_fdot2(__builtin_bit_cast(half2v, w.z),
                                 __builtin_bit_cast(half2v, h.z), acc, false);
    acc = __builtin_amdgcn_fdot2(__builtin_bit_cast(half2v, w.w),
                                 __builtin_bit_cast(half2v, h.w), acc, false);
    return acc;
}
__device__ __forceinline__ int dot16q(uint4 w, uint4 h, int acc) {
    acc = __builtin_amdgcn_sdot4((int)w.x, (int)h.x, acc, false);
    acc = __builtin_amdgcn_sdot4((int)w.y, (int)h.y, acc, false);
    acc = __builtin_amdgcn_sdot4((int)w.z, (int)h.z, acc, false);
    acc = __builtin_amdgcn_sdot4((int)w.w, (int)h.w, acc, false);
    return acc;
}
__device__ __forceinline__ ushort f16b(float x) {
    return __builtin_bit_cast(ushort, (_Float16)x);
}

// ---------- job descriptors ----------
struct GJob {   // one direction's chunk GEMM
    const void*  A;     // f16 path: emb (f32); i8 path: H08
    const int*   tok;   // f16 gather only
    const void*  W;     // f16: ushort*; i8: uint*
    const float* sw;    // i8 only (per-row scale)
    const float* bias;
    ushort*      out;   // f16 xg chunk (one dir)
    int tb, ts, is8, pad;
};
struct SJob {
    const ushort* xgF; const ushort* xgB;   // f16 xg [B][TC][1024]
    const uint*  wTq; const float* swf; const float* bhh2;
    ushort* hout; unsigned char* hout8; float* state;
    int doW8, tbF, tbB, doInit;
};
struct MegaP {
    SJob s;
    GJob g[4];
    int nScan, nGemm;
};

// ---------- device bodies ----------
__device__ __forceinline__ int pad4(int r) { return r + (r >> 3); }

// f16 GEMM (layer 0, K=128, emb gather), 1024 thr, one 128x128 tile, 4x4 microtile
__device__ void gemm16_dev(unsigned char* sm, const GJob& G, int bx, int by) {
    uint4* As = (uint4*)sm;          // [2][144]
    uint4* Bs = As + 288;
    const int tid = threadIdx.x;
    const int m0 = bx * 128, n0 = by * 128;
    const int lr = tid & 127, lk8 = (tid >> 7) & 1;
    const int lpad = lr + (lr >> 3);
    const bool isA = tid < 256, isB = (tid >= 256 && tid < 512);
    const int tcc = (m0 + lr) & (TC - 1);
    const int bb  = (m0 + lr) >> TCLOG;
    const int tglob = G.tb + G.ts * tcc;
    const long arow = (long)bb * SS + tglob;
    const float*  Af = isA ? ((const float*)G.A + (long)G.tok[arow] * 128 + lk8 * 8) : nullptr;
    const ushort* Wp = isB ? ((const ushort*)G.W + (long)(n0 + lr) * 128 + lk8 * 8) : nullptr;
    const int tr = tid >> 5, tn = tid & 31;

    float acc[4][4];
    #pragma unroll
    for (int i = 0; i < 4; i++)
        #pragma unroll
        for (int j = 0; j < 4; j++) acc[i][j] = 0.f;

    #pragma unroll 1
    for (int k0 = 0; k0 < 128; k0 += 16) {
        if (isA) {
            float4 a0 = *(const float4*)(Af + k0);
            float4 a1 = *(const float4*)(Af + k0 + 4);
            uint4 aw;
            aw.x = (uint)f16b(a0.x) | ((uint)f16b(a0.y) << 16);
            aw.y = (uint)f16b(a0.z) | ((uint)f16b(a0.w) << 16);
            aw.z = (uint)f16b(a1.x) | ((uint)f16b(a1.y) << 16);
            aw.w = (uint)f16b(a1.z) | ((uint)f16b(a1.w) << 16);
            As[lk8 * 144 + lpad] = aw;
        } else if (isB) {
            Bs[lk8 * 144 + lpad] = *(const uint4*)(Wp + k0);
        }
        __syncthreads();
        #pragma unroll
        for (int k8 = 0; k8 < 2; k8++) {
            uint4 a[4], w[4];
            #pragma unroll
            for (int i = 0; i < 4; i++) {
                a[i] = As[k8 * 144 + pad4(tr * 4 + i)];
                w[i] = Bs[k8 * 144 + pad4(tn * 4 + i)];
            }
            #pragma unroll
            for (int i = 0; i < 4; i++)
                #pragma unroll
                for (int j = 0; j < 4; j++)
                    acc[i][j] = dot8h(w[j], a[i], acc[i][j]);
        }
        __syncthreads();
    }

    float4 bc = *(const float4*)(G.bias + n0 + tn * 4);
    #pragma unroll
    for (int i = 0; i < 4; i++) {
        ushort4 o;
        o.x = f16b(acc[i][0] + bc.x);
        o.y = f16b(acc[i][1] + bc.y);
        o.z = f16b(acc[i][2] + bc.z);
        o.w = f16b(acc[i][3] + bc.w);
        *(ushort4*)(G.out + (long)(m0 + tr * 4 + i) * G4 + n0 + tn * 4) = o;
    }
}

// int8 GEMM (layer 1, K=512, A = H08), 1024 thr, one 128x128 tile, 4x4 microtile
__device__ void gemm8_dev(unsigned char* sm, const GJob& G, int bx, int by) {
    uint4* As = (uint4*)sm;          // [144]
    uint4* Bs = As + 144;
    const int tid = threadIdx.x;
    const int m0 = bx * 128, n0 = by * 128;
    const int lr = tid & 127;
    const int lpad = lr + (lr >> 3);
    const bool isA = tid < 128, isB = (tid >= 128 && tid < 256);
    const int tcc = (m0 + lr) & (TC - 1);
    const int bb  = (m0 + lr) >> TCLOG;
    const int tglob = G.tb + G.ts * tcc;
    const long arow = (long)bb * SS + tglob;
    const uint4* Ap = isA ? (const uint4*)((const unsigned char*)G.A + arow * 512) : nullptr;
    const uint4* Wp = isB ? ((const uint4*)G.W + (long)(n0 + lr) * 32) : nullptr;
    const int tr = tid >> 5, tn = tid & 31;

    int acc[4][4];
    #pragma unroll
    for (int i = 0; i < 4; i++)
        #pragma unroll
        for (int j = 0; j < 4; j++) acc[i][j] = 0;

    #pragma unroll 1
    for (int k0 = 0; k0 < 32; k0++) {
        if (isA) As[lpad] = Ap[k0];
        else if (isB) Bs[lpad] = Wp[k0];
        __syncthreads();
        uint4 a[4], w[4];
        #pragma unroll
        for (int i = 0; i < 4; i++) {
            a[i] = As[pad4(tr * 4 + i)];
            w[i] = Bs[pad4(tn * 4 + i)];
        }
        #pragma unroll
        for (int i = 0; i < 4; i++)
            #pragma unroll
            for (int j = 0; j < 4; j++)
                acc[i][j] = dot16q(w[j], a[i], acc[i][j]);
        __syncthreads();
    }

    #pragma unroll
    for (int i = 0; i < 4; i++) {
        ushort4 o;
        #pragma unroll
        for (int j = 0; j < 4; j++) {
            float r = fmaf((float)acc[i][j], G.sw[n0 + tn * 4 + j], G.bias[n0 + tn * 4 + j]);
            ((ushort*)&o)[j] = f16b(r);
        }
        *(ushort4*)(G.out + (long)(m0 + tr * 4 + i) * G4 + n0 + tn * 4) = o;
    }
}

// int8-dot LSTM scan (round-20 proven body; xg is f16)
__device__ void scan_dev(unsigned char* sm, const SJob& S, int b, int d) {
    const int j = threadIdx.x;
    const ushort* xg = (d ? S.xgB : S.xgF) + (long)b * TC * G4 + j;
    const uint4* wTd = (const uint4*)S.wTq + (long)d * 16 * 1024;

    uint4* lwq = (uint4*)sm;                      // 147456 B
    float* gl  = (float*)(sm + 147456);           // 4096 B
    uint*  hq  = (uint*)(sm + 147456 + 4096);     // 2x64 uints = 512 B

    #pragma unroll
    for (int kc = 0; kc < KLQ; kc++)
        lwq[kc * 1024 + j] = wTd[(long)kc * 1024 + j];

    const float bj  = S.bhh2[d * G4 + j];
    const float scl = S.swf[d * G4 + j];
    float c_reg = 0.f, h_reg = 0.f;
    if (j < HH) {
        if (!S.doInit) {
            h_reg = S.state[((d * BB + b) * 2 + 0) * HH + j];
            c_reg = S.state[((d * BB + b) * 2 + 1) * HH + j];
        }
        ((char*)hq)[j] = (char)__float2int_rn(h_reg * 127.f);
    }
    __syncthreads();

    #pragma unroll 1
    for (int tc = 0; tc < TC; ++tc) {
        const int rb = tc & 1;
        const uint4* hc = (const uint4*)(hq + rb * 64);
        int isum = 0;
        #pragma unroll
        for (int kc = 0; kc < KLQ; kc++)
            isum = dot16q(lwq[kc * 1024 + j], hc[kc], isum);
        #pragma unroll
        for (int kc = KLQ; kc < 16; kc++)
            isum = dot16q(wTd[(long)kc * 1024 + j], hc[kc], isum);

        float xv = (float)__builtin_bit_cast(_Float16, xg[(long)tc * G4]);
        gl[j] = fmaf((float)isum, scl, xv + bj);
        __syncthreads();
        if (j < HH) {
            float gi = gl[j], gf = gl[j + 256], gg = gl[j + 512], go = gl[j + 768];
            c_reg = sigf(gf) * c_reg + sigf(gi) * tanhfast(gg);
            float h = sigf(go) * tanhfast(c_reg);
            h_reg = h;
            int qh = __float2int_rn(h * 127.f);
            ((char*)(hq + (rb ^ 1) * 64))[j] = (char)qh;
            const int t = d ? (S.tbB - tc) : (S.tbF + tc);
            if (S.doW8) S.hout8[((long)(b * SS + t)) * 512 + d * HH + j] = (unsigned char)(char)qh;
            else        S.hout [((long)(b * SS + t)) * 512 + d * HH + j] = f16b(h);
        }
        __syncthreads();
    }

    if (j < HH) {
        S.state[((d * BB + b) * 2 + 0) * HH + j] = h_reg;
        S.state[((d * BB + b) * 2 + 1) * HH + j] = c_reg;
    }
}

// ---------- mega kernel: scan blocks first, then gemm tiles ----------
__global__ __launch_bounds__(1024, 4) void mega(MegaP p) {
    __shared__ __align__(16) unsigned char sm[152064];
    const int blk = blockIdx.x;
    if (blk < p.nScan * 128) {
        const int local = blk & 127;
        scan_dev(sm, p.s, local & 63, local >> 6);
    } else {
        const int gb = blk - p.nScan * 128;
        const int job = gb >> 9, t = gb & 511;
        const GJob& G = p.g[job];
        if (G.is8) gemm8_dev(sm, G, t & 63, t >> 6);
        else       gemm16_dev(sm, G, t & 63, t >> 6);
    }
}

// ---------- preprocessing (round-20 proven) ----------
__global__ void quant_whh(const float* __restrict__ whh, uint* __restrict__ wTq,
                          float* __restrict__ swf) {
    const int row = blockIdx.x;
    const int t = threadIdx.x;
    float4 v = *(const float4*)(whh + (long)row * 256 + t * 4);
    float mx = fmaxf(fmaxf(fabsf(v.x), fabsf(v.y)), fmaxf(fabsf(v.z), fabsf(v.w)));
    #pragma unroll
    for (int o = 32; o > 0; o >>= 1) mx = fmaxf(mx, __shfl_xor(mx, o));
    float inv = (mx > 0.f) ? 127.f / mx : 0.f;
    int q0 = (int)rintf(v.x * inv) & 255;
    int q1 = (int)rintf(v.y * inv) & 255;
    int q2 = (int)rintf(v.z * inv) & 255;
    int q3 = (int)rintf(v.w * inv) & 255;
    uint u = (uint)q0 | ((uint)q1 << 8) | ((uint)q2 << 16) | ((uint)q3 << 24);
    const int dir = row >> 10, j = row & 1023;
    const int kc = t >> 2, l4 = t & 3;
    wTq[(((long)(dir * 16 + kc) * 1024 + j) << 2) + l4] = u;
    if (t == 0) swf[row] = (mx > 0.f) ? (mx / 127.f) * (1.f / 127.f) : 0.f;
}

__global__ void quant_wih1(const float* __restrict__ w, uint* __restrict__ wq,
                           float* __restrict__ swf) {
    const int row = blockIdx.x;
    const int t = threadIdx.x;
    float4 a = *(const float4*)(w + (long)row * 512 + t * 8);
    float4 b = *(const float4*)(w + (long)row * 512 + t * 8 + 4);
    float mx = fmaxf(fmaxf(fmaxf(fabsf(a.x), fabsf(a.y)), fmaxf(fabsf(a.z), fabsf(a.w))),
                     fmaxf(fmaxf(fabsf(b.x), fabsf(b.y)), fmaxf(fabsf(b.z), fabsf(b.w))));
    #pragma unroll
    for (int o = 32; o > 0; o >>= 1) mx = fmaxf(mx, __shfl_xor(mx, o));
    float inv = (mx > 0.f) ? 127.f / mx : 0.f;
    uint q0 = (uint)((int)rintf(a.x * inv) & 255) | ((uint)((int)rintf(a.y * inv) & 255) << 8)
            | ((uint)((int)rintf(a.z * inv) & 255) << 16) | ((uint)((int)rintf(a.w * inv) & 255) << 24);
    uint q1 = (uint)((int)rintf(b.x * inv) & 255) | ((uint)((int)rintf(b.y * inv) & 255) << 8)
            | ((uint)((int)rintf(b.z * inv) & 255) << 16) | ((uint)((int)rintf(b.w * inv) & 255) << 24);
    wq[(long)row * 128 + t * 2]     = q0;
    wq[(long)row * 128 + t * 2 + 1] = q1;
    if (t == 0) swf[row] = (mx > 0.f) ? mx / (127.f * 127.f) : 0.f;
}

__global__ void pack_f16(const float* __restrict__ in, ushort* __restrict__ out, int n8) {
    int i = blockIdx.x * 256 + threadIdx.x;
    if (i >= n8) return;
    float4 a = *(const float4*)(in + (long)i * 8);
    float4 b = *(const float4*)(in + (long)i * 8 + 4);
    _Float16 o[8] = {(_Float16)a.x, (_Float16)a.y, (_Float16)a.z, (_Float16)a.w,
                     (_Float16)b.x, (_Float16)b.y, (_Float16)b.z, (_Float16)b.w};
    *(uint4*)(out + (long)i * 8) = *(uint4*)o;
}

// ---------- tail kernels (round-20 proven) ----------
__global__ __launch_bounds__(256) void emissions_k16(
    const ushort* __restrict__ h1, const float* __restrict__ clsw,
    const float* __restrict__ clsb, float* __restrict__ em)
{
    long u = (long)blockIdx.x * 256 + threadIdx.x;
    if (u >= (long)BB * SS * NC) return;
    int c = (int)(u % NC);
    long m = u / NC;
    const uint* hr = (const uint*)(h1 + m * 512);
    const float2* wr = (const float2*)(clsw + (long)c * 512);
    float s0 = 0, s1 = 0;
    #pragma unroll 8
    for (int q = 0; q < 256; q += 2) {
        half2v h0 = __builtin_bit_cast(half2v, hr[q]);
        half2v h1v = __builtin_bit_cast(half2v, hr[q + 1]);
        float2 w0 = wr[q], w1 = wr[q + 1];
        s0 += (float)h0.x * w0.x + (float)h0.y * w0.y;
        s1 += (float)h1v.x * w1.x + (float)h1v.y * w1.y;
    }
    em[u] = s0 + s1 + clsb[c];
}

__global__ __launch_bounds__(64) void crf_llh(
    const float* __restrict__ em, const int* __restrict__ labels,
    const int* __restrict__ mask, const float* __restrict__ start,
    const float* __restrict__ endt, const float* __restrict__ trans,
    float* __restrict__ llh)
{
    int b = blockIdx.x, j = threadIdx.x;
    bool act = j < NC;
    float tcol[NC];
    #pragma unroll
    for (int i = 0; i < NC; i++) tcol[i] = act ? trans[i * NC + j] : 0.f;
    const float* emb_ = em + (long)b * SS * NC;
    const int* lb = labels + b * SS;
    const int* mk = mask + b * SS;
    float alpha = act ? (start[j] + emb_[j]) : -1e30f;

    float num = 0.f;
    int msum = 0;
    for (int t = j; t < SS; t += 64) msum += (mk[t] != 0);
    for (int t = 1 + j; t < SS; t += 64) {
        float m = (float)mk[t];
        num += m * (trans[lb[t - 1] * NC + lb[t]] + emb_[t * NC + lb[t]]);
    }
    for (int o = 32; o > 0; o >>= 1) {
        num  += __shfl_down(num, o);
        msum += __shfl_down(msum, o);
    }
    msum = __shfl(msum, 0);

    for (int t = 1; t < SS; t++) {
        int m = mk[t];
        float emj = act ? emb_[t * NC + j] : 0.f;
        float v[NC];
        float mx = -1e30f;
        #pragma unroll
        for (int i = 0; i < NC; i++) {
            v[i] = __shfl(alpha, i) + tcol[i];
            mx = fmaxf(mx, v[i]);
        }
        float sum = 0.f;
        #pragma unroll
        for (int i = 0; i < NC; i++) sum += __expf(v[i] - mx);
        float nxt = mx + __logf(sum) + emj;
        if (m > 0 && act) alpha = nxt;
    }
    float fin = act ? alpha + endt[j] : -1e30f;
    float mx = -1e30f;
    #pragma unroll
    for (int i = 0; i < NC; i++) mx = fmaxf(mx, __shfl(fin, i));
    float s = 0.f;
    #pragma unroll
    for (int i = 0; i < NC; i++) s += __expf(__shfl(fin, i) - mx);
    float den = mx + __logf(s);
    if (j == 0) {
        int last_idx = msum - 1;
        float numer = num + start[lb[0]] + emb_[lb[0]] + endt[lb[last_idx]];
        llh[b] = numer - den;
    }
}

__global__ __launch_bounds__(64) void loss_k(const float* __restrict__ llh, float* __restrict__ out) {
    int j = threadIdx.x;
    float v = llh[j];
    for (int o = 32; o > 0; o >>= 1) v += __shfl_down(v, o);
    if (j == 0) out[0] = -v / 64.0f;
}

__global__ __launch_bounds__(64) void viterbi_k(
    const float* __restrict__ em, const int* __restrict__ mask,
    const float* __restrict__ start, const float* __restrict__ endt,
    const float* __restrict__ trans, float* __restrict__ outp)
{
    int b = blockIdx.x, j = threadIdx.x;
    bool act = j < NC;
    __shared__ unsigned char bp[SS][NC];
    float tcol[NC];
    #pragma unroll
    for (int i = 0; i < NC; i++) tcol[i] = act ? trans[i * NC + j] : 0.f;
    const float* emb_ = em + (long)b * SS * NC;
    const int* mk = mask + b * SS;
    float score = act ? (start[j] + emb_[j]) : -1e30f;

    for (int t = 1; t < SS; t++) {
        float best = 0.f;
        int bi = 0;
        #pragma unroll
        for (int i = 0; i < NC; i++) {
            float vv = __shfl(score, i) + tcol[i];
            if (i == 0 || vv > best) { best = vv; bi = i; }
        }
        int m = mk[t];
        float nxt = best + (act ? emb_[t * NC + j] : 0.f);
        if (act) {
            if (m > 0) { score = nxt; bp[t][j] = (unsigned char)bi; }
            else       { bp[t][j] = (unsigned char)j; }
        }
    }
    float fin = act ? score + endt[j] : -1e30f;
    float bestf = 0.f;
    int last = 0;
    #pragma unroll
    for (int i = 0; i < NC; i++) {
        float vv = __shfl(fin, i);
        if (i == 0 || vv > bestf) { bestf = vv; last = i; }
    }
    __syncthreads();
    if (j == 0) {
        int cur = last;
        outp[1 + (long)b * SS + (SS - 1)] = (float)cur;
        for (int t = SS - 1; t >= 1; t--) {
            cur = bp[t][cur];
            outp[1 + (long)b * SS + (t - 1)] = (float)cur;
        }
    }
}

extern "C" void kernel_launch(void* const* d_in, const int* in_sizes, int n_in,
                              void* d_out, int out_size, void* d_ws, size_t ws_size,
                              hipStream_t stream) {
    const int*   tok    = (const int*)d_in[0];
    const int*   lab    = (const int*)d_in[1];
    const int*   msk    = (const int*)d_in[2];
    const float* emb    = (const float*)d_in[3];
    const float* w_ih0  = (const float*)d_in[4];
    const float* w_hh0  = (const float*)d_in[5];
    const float* b_ih0  = (const float*)d_in[6];
    const float* b_hh0  = (const float*)d_in[7];
    const float* w_ih1  = (const float*)d_in[8];
    const float* w_hh1  = (const float*)d_in[9];
    const float* b_ih1  = (const float*)d_in[10];
    const float* b_hh1  = (const float*)d_in[11];
    const float* clsw   = (const float*)d_in[12];
    const float* clsb   = (const float*)d_in[13];
    const float* startt = (const float*)d_in[14];
    const float* endt   = (const float*)d_in[15];
    const float* transm = (const float*)d_in[16];
    float* out = (float*)d_out;

    // ---- workspace carve (f32 units); ~194 MB < proven >=207 MB ws ----
    size_t nH8  = (size_t)BB * SS * 512 / 4;       // int8 H0
    size_t nHh  = (size_t)BB * SS * 512 / 2;       // f16 H1
    size_t xgHalf = (size_t)BB * TC * G4;          // ushorts per dir per chunk
    size_t nXGb = xgHalf * 2 / 2;                  // f32 units per buffer (both dirs f16)
    size_t nWQ  = (size_t)2 * 16 * 1024 * 4;
    size_t nSW  = (size_t)2 * 1024;
    size_t nWI0 = (size_t)2048 * 128 / 2;
    size_t nWQ1 = (size_t)2048 * 128;
    size_t nEM  = (size_t)BB * SS * NC;
    size_t nST  = (size_t)2 * BB * 2 * HH;

    float* H08f = (float*)d_ws;
    float* H1f  = H08f + nH8;
    float* XG0a = H1f + nHh;           // L0 parity 0
    float* XG0b = XG0a + nXGb;         // L0 parity 1
    float* XG1a = XG0b + nXGb;         // L1 parity 0
    float* XG1b = XG1a + nXGb;         // L1 parity 1
    float* WQ0  = XG1b + nXGb;
    float* WQ1w = WQ0 + nWQ;
    float* SW0  = WQ1w + nWQ;
    float* SW1  = SW0 + nSW;
    float* WI0  = SW1 + nSW;
    float* WQI1 = WI0 + nWI0;
    float* SWI1 = WQI1 + nWQ1;
    float* EM   = SWI1 + 2048;
    float* ST0  = EM + nEM;
    float* ST1  = ST0 + nST;
    float* LLH  = ST1 + nST;

    unsigned char* H08 = (unsigned char*)H08f;
    ushort* H1h  = (ushort*)H1f;
    ushort* WI0h = (ushort*)WI0;
    ushort* XG0[2] = {(ushort*)XG0a, (ushort*)XG0b};
    ushort* XG1[2] = {(ushort*)XG1a, (ushort*)XG1b};

    quant_whh<<<2048, 64, 0, stream>>>(w_hh0, (uint*)WQ0, SW0);
    quant_whh<<<2048, 64, 0, stream>>>(w_hh1, (uint*)WQ1w, SW1);
    quant_wih1<<<2048, 64, 0, stream>>>(w_ih1, (uint*)WQI1, SWI1);
    pack_f16<<<(2048 * 128 / 8 + 255) / 256, 256, 0, stream>>>(w_ih0, WI0h, 2048 * 128 / 8);

    auto g16 = [&](int c, int dd) {
        GJob g{};
        g.A = emb; g.tok = tok;
        g.W = WI0h + (size_t)dd * 1024 * 128;
        g.sw = nullptr; g.bias = b_ih0 + dd * 1024;
        g.out = XG0[c & 1] + (size_t)dd * xgHalf;
        g.tb = dd ? (SS - 1 - c * TC) : (c * TC);
        g.ts = dd ? -1 : 1;
        g.is8 = 0;
        return g;
    };
    auto g8 = [&](int c, int dd) {
        GJob g{};
        g.A = H08; g.tok = nullptr;
        g.W = (const uint*)WQI1 + (size_t)dd * 1024 * 128;
        g.sw = SWI1 + dd * 1024; g.bias = b_ih1 + dd * 1024;
        g.out = XG1[c & 1] + (size_t)dd * xgHalf;
        g.tb = dd ? (SS - 1 - c * TC) : (c * TC);
        g.ts = dd ? -1 : 1;
        g.is8 = 1;
        return g;
    };
    auto sj = [&](int layer, int c) {
        SJob s{};
        ushort* xgb = layer ? XG1[c & 1] : XG0[c & 1];
        s.xgF = xgb; s.xgB = xgb + xgHalf;
        s.wTq = (const uint*)(layer ? WQ1w : WQ0);
        s.swf = layer ? SW1 : SW0;
        s.bhh2 = layer ? b_hh1 : b_hh0;
        s.hout = H1h; s.hout8 = H08;
        s.doW8 = layer ? 0 : 1;
        s.state = layer ? ST1 : ST0;
        s.tbF = c * TC; s.tbB = SS - 1 - c * TC;
        s.doInit = (c == 0);
        return s;
    };
    auto launch = [&](int nS, SJob s, GJob* gj, int nG) {
        MegaP p{};
        p.s = s;
        for (int i = 0; i < nG; i++) p.g[i] = gj[i];
        p.nScan = nS; p.nGemm = nG;
        mega<<<nS * 128 + nG * 512, 1024, 0, stream>>>(p);
    };

    // ---- layer 0 pipeline ----
    { GJob j2[2] = {g16(0, 0), g16(0, 1)};        launch(0, SJob{}, j2, 2); }   // D1
    { GJob j2[2] = {g16(1, 0), g16(1, 1)};        launch(1, sj(0, 0), j2, 2); } // D2
    { GJob j2[2] = {g16(2, 0), g16(2, 1)};        launch(1, sj(0, 1), j2, 2); } // D3
    { GJob j2[2] = {g16(3, 0), g16(3, 1)};        launch(1, sj(0, 2), j2, 2); } // D4
    {                                              launch(1, sj(0, 3), nullptr, 0); } // D5
    // ---- layer 1 pipeline (L0 fully done; bridge gemms for c0,c1) ----
    { GJob j4[4] = {g8(0, 0), g8(0, 1), g8(1, 0), g8(1, 1)}; launch(0, SJob{}, j4, 4); } // D6
    {                                              launch(1, sj(1, 0), nullptr, 0); } // D7
    { GJob j2[2] = {g8(2, 0), g8(2, 1)};          launch(1, sj(1, 1), j2, 2); } // D8
    { GJob j2[2] = {g8(3, 0), g8(3, 1)};          launch(1, sj(1, 2), j2, 2); } // D9
    {                                              launch(1, sj(1, 3), nullptr, 0); } // D10

    emissions_k16<<<((BB * SS * NC) + 255) / 256, 256, 0, stream>>>(H1h, clsw, clsb, EM);
    crf_llh<<<BB, 64, 0, stream>>>(EM, lab, msk, startt, endt, transm, LLH);
    loss_k<<<1, 64, 0, stream>>>(LLH, out);
    viterbi_k<<<BB, 64, 0, stream>>>(EM, msk, startt, endt, transm, out);
}